// Round 21
// baseline (29.478 us; speedup 1.0000x reference)
//
#include <hip/hip_runtime.h>
#include <math.h>
#include <stdint.h>

#define BROWS 262144
#define KCLS  101
#define ROWB  404
#define RPB   16                      // rows per batch (per wave)
#define BATCHB (RPB * ROWB)           // 6464 B
#define STAGEB 6656                   // 6x1024 (w16) + 2x256 (w4); 192 B junk
#define TOTB  (BROWS * ROWB)          // 105,906,176 B
#define NBLK  2048                    // 8 blocks/CU resident (validated optimum)
#define NBPW  8                       // batches per block

typedef const __attribute__((address_space(1))) uint32_t* gptr_t;
typedef __attribute__((address_space(3))) uint32_t*       lptr_t;

// Stage one 16-row batch (6464 B real, 6656 staged) into LDS.
// 8 issues: 6 x width-16 + 2 x width-4. ONLY widths 4/16 are HW-verified
// (width-12 corrupted LDS in r19 -> NaN).
__device__ __forceinline__ void stage_batch(const char* base, unsigned off,
                                            char* dst, int lane) {
#pragma unroll
    for (int k = 0; k < 6; ++k) {
        unsigned o = off + (unsigned)(k * 1024 + lane * 16);
        o = (o > (unsigned)(TOTB - 16)) ? (unsigned)(TOTB - 16) : o;
        __builtin_amdgcn_global_load_lds((gptr_t)(base + o),
                                         (lptr_t)(dst + k * 1024), 16, 0, 0);
    }
#pragma unroll
    for (int k = 0; k < 2; ++k) {
        unsigned o = off + (unsigned)(6144 + k * 256 + lane * 4);
        o = (o > (unsigned)(TOTB - 4)) ? (unsigned)(TOTB - 4) : o;
        __builtin_amdgcn_global_load_lds((gptr_t)(base + o),
                                         (lptr_t)(dst + 6144 + k * 256), 4, 0, 0);
    }
}

// 4 lanes per row: lane q owns classes [25q, 25q+n), n = 25,25,25,26.
// Lane-local streams + prefix-offset merge (validated, absmax 0.0).
// Single-wave blocks, no barriers. TRUE depth-2 pipeline: 3 LDS buffers,
// batches k+1 AND k+2 in flight during compute(k); stage(k+3) issued into
// the buffer compute(k) just freed. Slack per batch = 2 compute phases.
extern "C" __global__ void __launch_bounds__(64)
ord_main(const float* __restrict__ logit,
         const int*   __restrict__ labels,
         const float* __restrict__ cw,
         float*       __restrict__ partial)
{
    __shared__ __align__(16) char smem[3 * STAGEB];    // 19968 B -> 8 blocks/CU
    const int lane = threadIdx.x;
    const int q    = lane & 3;
    const int g    = lane >> 2;                        // row within batch, 0..15
    const char* gb = (const char*)logit;
    const unsigned woff = (unsigned)blockIdx.x * (unsigned)(RPB * NBPW * ROWB);

    // ---- prologue: stage batches 0,1,2 (24 vmcnt-tracked issues) ----
    stage_batch(gb, woff, smem, lane);
    stage_batch(gb, woff + (unsigned)BATCHB, smem + STAGEB, lane);
    stage_batch(gb, woff + (unsigned)(2 * BATCHB), smem + 2 * STAGEB, lane);

    // ---- labels/weights -> registers (compiler-managed wait; prologue-only) ----
    const int rbase = blockIdx.x * (RPB * NBPW);
    const int   yv0 = labels[rbase + lane];
    const int   yv1 = labels[rbase + 64 + lane];
    const float wv0 = cw[yv0];
    const float wv1 = cw[yv1];

    const float inv_logK = 1.0f / logf(101.0f);        // folds at compile time
    const float invK     = 1.0f / 101.0f;
    const int   t0 = 25 * q;
    const int   nn = (q == 3) ? 26 : 25;
    const float nq = (float)nn;

    float tacc = 0.0f;

#pragma unroll
    for (int k = 0; k < NBPW; ++k) {
        // wait: batch k's 8 issues done; later batches stay in flight.
        // outstanding entering wait: k<=5 -> 24, k==6 -> 16, k==7 -> 8.
        if (k < 6)       { asm volatile("s_waitcnt vmcnt(16)" ::: "memory"); }
        else if (k == 6) { asm volatile("s_waitcnt vmcnt(8)"  ::: "memory"); }
        else             { asm volatile("s_waitcnt vmcnt(0)"  ::: "memory"); }

        const float* rowb = (const float*)(smem + (k % 3) * STAGEB) + g * KCLS;
        const float* lrow = rowb + t0;
        const int   idx = k * 16 + g;                  // k compile-time (unrolled)
        const int   y   = (k < 4) ? __shfl(yv0, idx, 64) : __shfl(yv1, idx - 64, 64);
        const float wy  = (k < 4) ? __shfl(wv0, idx, 64) : __shfl(wv1, idx - 64, 64);
        const float yf  = (float)y;

        // ---- lane-local stream over 25 (+1 for q==3) classes ----
        float a = 0.f, w = 0.f, sp = 0.f, tl = 0.f, bm = 0.f, cm = 0.f;
        float us = 0.f, ef = 0.f, ep = 0.f;
#pragma unroll
        for (int i = 0; i < 25; ++i) {
            const int   t = t0 + i;
            const float e = __expf(lrow[i]);           // no max-shift: |x| < ~6
            if (i == 0) ef = e; else us += __builtin_fabsf(e - ep);
            a += e;                                    // local inclusive prefix L_i
            w += a;                                    // sum L_i
            sp = __builtin_fmaf(a, a, sp);             // sum L_i^2
            tl += (t <= y) ? a : 0.0f;                 // masked sum L_i
            bm = __builtin_fmaf(e, (float)t, bm);      // sum e*t
            cm = __builtin_fmaf(e, (float)(t * t), cm);// sum e*t^2
            ep = e;
        }
        if (q == 3) {                                  // class 100
            const float e = __expf(lrow[25]);
            us += __builtin_fabsf(e - ep);
            a += e; w += a;
            sp = __builtin_fmaf(a, a, sp);
            tl += (y >= 100) ? a : 0.0f;
            bm = __builtin_fmaf(e, 100.0f, bm);
            cm = __builtin_fmaf(e, 10000.0f, cm);
            ep = e;
        }

        // ---- 4-lane merge ----
        float incl = a;
        { float u = __shfl_up(incl, 1, 4); incl += (q >= 1) ? u : 0.0f; }
        { float u = __shfl_up(incl, 2, 4); incl += (q >= 2) ? u : 0.0f; }
        const float S   = __shfl(incl, 3, 4);          // row total
        const float E   = incl - a;                    // exclusive e-prefix
        const float inv = __builtin_amdgcn_rcpf(S);
        const float nf  = __shfl_down(ef, 1, 4);       // next lane's first e (q==3 junk)

        int mi = y - t0 + 1; mi = (mi < 0) ? 0 : mi; mi = (mi > nn) ? nn : mi;
        const float spc  = __builtin_fmaf(nq * E, E, __builtin_fmaf(2.0f * E, w, sp));
        const float tlc  = __builtin_fmaf((float)mi, E, tl);
        const float eseC = __builtin_fmaf(yf, __builtin_fmaf(yf, a, -2.0f * bm), cm);
        const float uniC = us + ((q < 3) ? __builtin_fabsf(ep - nf) : 0.0f)
                         + ((q == 0) ? ef : 0.0f) + ((q == 3) ? ep : 0.0f);

        float part = (wy * 1.0e-4f * inv) * eseC;              // ESE
        part = __builtin_fmaf(invK * inv * inv, spc, part);    // EMD quad
        part = __builtin_fmaf(-2.0f * invK * inv, tlc, part);  // EMD cross
        part = __builtin_fmaf(0.00375f * inv, uniC, part);     // uni |delta|
        part += __shfl_xor(part, 1);
        part += __shfl_xor(part, 2);                           // group total

        // ---- epilogue (broadcast LDS reads; only q==0 accumulates) ----
        const int   ym = (y > 0)   ? y - 1 : 0;
        const int   yp = (y < 100) ? y + 1 : 100;
        const float xy = rowb[y];
        const float eY = __expf(xy);
        const float eL = (y > 0)   ? __expf(rowb[ym]) : 0.0f;
        const float eR = (y < 100) ? __expf(rowb[yp]) : 0.0f;
        const float lnS  = __logf(S);
        const float py   = eY * inv;
        const float tail = 1.0f - (eL + eY + eR) * inv;
        const float lp   = fmaxf(__builtin_fmaf(fmaxf(eL, eR), inv, 0.25f - py), 0.0f);
        const float extra = wy * (lnS - xy) * inv_logK         // CE
                          + 2.5f * (tail + lp)                 // tail + local peak
                          - 0.0075f * py                       // uni -2*cU*p_y
                          + invK * (float)(y + 1);             // EMD scalar remainder

        tacc += (q == 0) ? (part + extra) : 0.0f;

        // ---- stage batch k+3 into the buffer just freed (after compute) ----
        if (k + 3 < NBPW) {
            asm volatile("s_waitcnt lgkmcnt(0)" ::: "memory");  // drain ds_reads first
            stage_batch(gb, woff + (unsigned)((k + 3) * BATCHB),
                        smem + (k % 3) * STAGEB, lane);
        }
    }

    // ---- single-wave butterfly (deterministic) ----
    tacc += __shfl_xor(tacc, 1);
    tacc += __shfl_xor(tacc, 2);
    tacc += __shfl_xor(tacc, 4);
    tacc += __shfl_xor(tacc, 8);
    tacc += __shfl_xor(tacc, 16);
    tacc += __shfl_xor(tacc, 32);

    if (lane == 0) partial[blockIdx.x] = tacc;
}

extern "C" __global__ void __launch_bounds__(256)
ord_final(const float* __restrict__ partial, float* __restrict__ out, int n)
{
    float v = 0.0f;
    for (int i = threadIdx.x; i < n; i += 256) v += partial[i];

    v += __shfl_xor(v, 1);
    v += __shfl_xor(v, 2);
    v += __shfl_xor(v, 4);
    v += __shfl_xor(v, 8);
    v += __shfl_xor(v, 16);
    v += __shfl_xor(v, 32);

    __shared__ float sb[4];
    const int lane = threadIdx.x & 63;
    const int wid  = threadIdx.x >> 6;
    if (lane == 0) sb[wid] = v;
    __syncthreads();
    if (threadIdx.x == 0)
        out[0] = ((sb[0] + sb[1]) + (sb[2] + sb[3])) * (1.0f / (float)BROWS);
}

extern "C" void kernel_launch(void* const* d_in, const int* in_sizes, int n_in,
                              void* d_out, int out_size, void* d_ws, size_t ws_size,
                              hipStream_t stream)
{
    const float* logit  = (const float*)d_in[0];
    const int*   labels = (const int*)d_in[1];
    const float* cw     = (const float*)d_in[2];
    float*       part   = (float*)d_ws;

    hipLaunchKernelGGL(ord_main, dim3(NBLK), dim3(64), 0, stream,
                       logit, labels, cw, part);
    hipLaunchKernelGGL(ord_final, dim3(1), dim3(256), 0, stream,
                       part, (float*)d_out, NBLK);
}

// Round 22
// 28.000 us; speedup vs baseline: 1.0528x; 1.0528x over previous
//
#include <hip/hip_runtime.h>
#include <math.h>
#include <stdint.h>

#define BROWS 262144
#define KCLS  101
#define ROWB  404
#define RPB   16                      // rows per batch (per wave)
#define BATCHB (RPB * ROWB)           // 6464 B
#define STAGEB 7168                   // 7 x 1KB width-16 issues (704 B pad; w12 is BROKEN on gfx950 - r19)
#define TOTB  (BROWS * ROWB)          // 105,906,176 B
#define NBLK  2048                    // 8 blocks/CU resident (validated optimum)
#define NBPW  8                       // batches per block

typedef const __attribute__((address_space(1))) uint32_t* gptr_t;
typedef __attribute__((address_space(3))) uint32_t*       lptr_t;

// Stage one 16-row batch (6464 B real, 7168 staged) into LDS.
// Width-16 ONLY (width-12 produced NaN corruption in r19).
__device__ __forceinline__ void stage_batch(const char* base, unsigned off,
                                            char* dst, int lane) {
#pragma unroll
    for (int k = 0; k < 7; ++k) {
        unsigned o = off + (unsigned)(k * 1024 + lane * 16);
        o = (o > (unsigned)(TOTB - 16)) ? (unsigned)(TOTB - 16) : o;
        __builtin_amdgcn_global_load_lds((gptr_t)(base + o),
                                         (lptr_t)(dst + k * 1024), 16, 0, 0);
    }
}

// 4 lanes per row: lane q owns classes [25q, 25q+n), n = 25,25,25,26.
// Lane-local streams + prefix-offset merge (validated, absmax 0.0).
// Single-wave blocks, no barriers, counted vmcnt(7).
// Pipeline: prologue stages batches 0 and 1; stage(k+2) issued AFTER
// compute(k) into the buffer compute just freed. Best measured: 28.7 us.
extern "C" __global__ void __launch_bounds__(64)
ord_main(const float* __restrict__ logit,
         const int*   __restrict__ labels,
         const float* __restrict__ cw,
         float*       __restrict__ partial)
{
    __shared__ __align__(16) char smem[2 * STAGEB];    // 14336 B
    const int lane = threadIdx.x;
    const int q    = lane & 3;
    const int g    = lane >> 2;                        // row within batch, 0..15
    const char* gb = (const char*)logit;
    const unsigned woff = (unsigned)blockIdx.x * (unsigned)(RPB * NBPW * ROWB);

    // ---- prologue: stage batches 0 AND 1 (14 vmcnt-tracked issues) ----
    stage_batch(gb, woff, smem, lane);
    stage_batch(gb, woff + (unsigned)BATCHB, smem + STAGEB, lane);

    // ---- labels/weights -> registers ----
    const int rbase = blockIdx.x * (RPB * NBPW);
    const int   yv0 = labels[rbase + lane];
    const int   yv1 = labels[rbase + 64 + lane];
    const float wv0 = cw[yv0];
    const float wv1 = cw[yv1];

    const float inv_logK = 1.0f / logf(101.0f);        // folds at compile time
    const float invK     = 1.0f / 101.0f;
    const int   t0 = 25 * q;
    const int   nn = (q == 3) ? 26 : 25;
    const float nq = (float)nn;

    float tacc = 0.0f;

#pragma unroll
    for (int k = 0; k < NBPW; ++k) {
        // batch k ready; later-issued stages stay in flight
        if (k == NBPW - 1) { asm volatile("s_waitcnt vmcnt(0)" ::: "memory"); }
        else               { asm volatile("s_waitcnt vmcnt(7)" ::: "memory"); }

        const float* rowb = (const float*)(smem + (k & 1) * STAGEB) + g * KCLS;
        const float* lrow = rowb + t0;
        const int   idx = k * 16 + g;                  // k compile-time (unrolled)
        const int   y   = (k < 4) ? __shfl(yv0, idx, 64) : __shfl(yv1, idx - 64, 64);
        const float wy  = (k < 4) ? __shfl(wv0, idx, 64) : __shfl(wv1, idx - 64, 64);
        const float yf  = (float)y;

        // ---- lane-local stream over 25 (+1 for q==3) classes ----
        float a = 0.f, w = 0.f, sp = 0.f, tl = 0.f, bm = 0.f, cm = 0.f;
        float us = 0.f, ef = 0.f, ep = 0.f;
#pragma unroll
        for (int i = 0; i < 25; ++i) {
            const int   t = t0 + i;
            const float e = __expf(lrow[i]);           // no max-shift: |x| < ~6
            if (i == 0) ef = e; else us += __builtin_fabsf(e - ep);
            a += e;                                    // local inclusive prefix L_i
            w += a;                                    // sum L_i
            sp = __builtin_fmaf(a, a, sp);             // sum L_i^2
            tl += (t <= y) ? a : 0.0f;                 // masked sum L_i
            bm = __builtin_fmaf(e, (float)t, bm);      // sum e*t
            cm = __builtin_fmaf(e, (float)(t * t), cm);// sum e*t^2
            ep = e;
        }
        if (q == 3) {                                  // class 100
            const float e = __expf(lrow[25]);
            us += __builtin_fabsf(e - ep);
            a += e; w += a;
            sp = __builtin_fmaf(a, a, sp);
            tl += (y >= 100) ? a : 0.0f;
            bm = __builtin_fmaf(e, 100.0f, bm);
            cm = __builtin_fmaf(e, 10000.0f, cm);
            ep = e;
        }

        // ---- 4-lane merge ----
        float incl = a;
        { float u = __shfl_up(incl, 1, 4); incl += (q >= 1) ? u : 0.0f; }
        { float u = __shfl_up(incl, 2, 4); incl += (q >= 2) ? u : 0.0f; }
        const float S   = __shfl(incl, 3, 4);          // row total
        const float E   = incl - a;                    // exclusive e-prefix
        const float inv = __builtin_amdgcn_rcpf(S);
        const float nf  = __shfl_down(ef, 1, 4);       // next lane's first e (q==3 junk)

        int mi = y - t0 + 1; mi = (mi < 0) ? 0 : mi; mi = (mi > nn) ? nn : mi;
        const float spc  = __builtin_fmaf(nq * E, E, __builtin_fmaf(2.0f * E, w, sp));
        const float tlc  = __builtin_fmaf((float)mi, E, tl);
        const float eseC = __builtin_fmaf(yf, __builtin_fmaf(yf, a, -2.0f * bm), cm);
        const float uniC = us + ((q < 3) ? __builtin_fabsf(ep - nf) : 0.0f)
                         + ((q == 0) ? ef : 0.0f) + ((q == 3) ? ep : 0.0f);

        float part = (wy * 1.0e-4f * inv) * eseC;              // ESE
        part = __builtin_fmaf(invK * inv * inv, spc, part);    // EMD quad
        part = __builtin_fmaf(-2.0f * invK * inv, tlc, part);  // EMD cross
        part = __builtin_fmaf(0.00375f * inv, uniC, part);     // uni |delta|
        part += __shfl_xor(part, 1);
        part += __shfl_xor(part, 2);                           // group total

        // ---- epilogue (broadcast LDS reads; only q==0 accumulates) ----
        const int   ym = (y > 0)   ? y - 1 : 0;
        const int   yp = (y < 100) ? y + 1 : 100;
        const float xy = rowb[y];
        const float eY = __expf(xy);
        const float eL = (y > 0)   ? __expf(rowb[ym]) : 0.0f;
        const float eR = (y < 100) ? __expf(rowb[yp]) : 0.0f;
        const float lnS  = __logf(S);
        const float py   = eY * inv;
        const float tail = 1.0f - (eL + eY + eR) * inv;
        const float lp   = fmaxf(__builtin_fmaf(fmaxf(eL, eR), inv, 0.25f - py), 0.0f);
        const float extra = wy * (lnS - xy) * inv_logK         // CE
                          + 2.5f * (tail + lp)                 // tail + local peak
                          - 0.0075f * py                       // uni -2*cU*p_y
                          + invK * (float)(y + 1);             // EMD scalar remainder

        tacc += (q == 0) ? (part + extra) : 0.0f;

        // ---- stage batch k+2 into the buffer just freed (after compute) ----
        if (k + 2 < NBPW) {
            // guard: drain pending ds_reads before async LDS overwrite
            asm volatile("s_waitcnt lgkmcnt(0)" ::: "memory");
            stage_batch(gb, woff + (unsigned)((k + 2) * BATCHB),
                        smem + (k & 1) * STAGEB, lane);
        }
    }

    // ---- single-wave butterfly (deterministic) ----
    tacc += __shfl_xor(tacc, 1);
    tacc += __shfl_xor(tacc, 2);
    tacc += __shfl_xor(tacc, 4);
    tacc += __shfl_xor(tacc, 8);
    tacc += __shfl_xor(tacc, 16);
    tacc += __shfl_xor(tacc, 32);

    if (lane == 0) partial[blockIdx.x] = tacc;
}

extern "C" __global__ void __launch_bounds__(256)
ord_final(const float* __restrict__ partial, float* __restrict__ out, int n)
{
    float v = 0.0f;
    for (int i = threadIdx.x; i < n; i += 256) v += partial[i];

    v += __shfl_xor(v, 1);
    v += __shfl_xor(v, 2);
    v += __shfl_xor(v, 4);
    v += __shfl_xor(v, 8);
    v += __shfl_xor(v, 16);
    v += __shfl_xor(v, 32);

    __shared__ float sb[4];
    const int lane = threadIdx.x & 63;
    const int wid  = threadIdx.x >> 6;
    if (lane == 0) sb[wid] = v;
    __syncthreads();
    if (threadIdx.x == 0)
        out[0] = ((sb[0] + sb[1]) + (sb[2] + sb[3])) * (1.0f / (float)BROWS);
}

extern "C" void kernel_launch(void* const* d_in, const int* in_sizes, int n_in,
                              void* d_out, int out_size, void* d_ws, size_t ws_size,
                              hipStream_t stream)
{
    const float* logit  = (const float*)d_in[0];
    const int*   labels = (const int*)d_in[1];
    const float* cw     = (const float*)d_in[2];
    float*       part   = (float*)d_ws;

    hipLaunchKernelGGL(ord_main, dim3(NBLK), dim3(64), 0, stream,
                       logit, labels, cw, part);
    hipLaunchKernelGGL(ord_final, dim3(1), dim3(256), 0, stream,
                       part, (float*)d_out, NBLK);
}